// Round 7
// baseline (467.401 us; speedup 1.0000x reference)
//
#include <hip/hip_runtime.h>
#include <stdint.h>

#define T_TOKENS 8192
#define D_DIM 512
#define F_DIM 2048
#define E_NUM 8
#define TILE_T 32          // tokens per ffn block (2 m-tiles)
#define N_TILES 256        // ceil(8192/32): worst-case routing coverage

typedef short short8 __attribute__((ext_vector_type(8)));
typedef float f32x4 __attribute__((ext_vector_type(4)));

// ---------------- bf16 helpers (RNE, finite inputs) -------------------------
__device__ __forceinline__ unsigned short f2bf(float f) {
    union { float f; unsigned int u; } c; c.f = f;
    unsigned int u = c.u;
    unsigned int r = (u + 0x7fffu + ((u >> 16) & 1u)) >> 16;
    return (unsigned short)r;
}
__device__ __forceinline__ unsigned int pack2(float a, float b) {
    return (unsigned int)f2bf(a) | ((unsigned int)f2bf(b) << 16);
}

// ws layout (bytes)
#define WS_COUNT 0
#define WS_PROBS 512
#define WS_TOK   16384
#define WS_WGT   (WS_TOK + E_NUM * T_TOKENS * 4)
#define WS_W1B   (1u << 20)
#define WS_W2B   (WS_W1B + 16777216u)

// ---------------------------------------------------------------------------
// Convert w1/w2 fp32 -> bf16 in MFMA B-fragment order:
//   frag-lane linear = ((e*(N/16) + ft)*(K/32) + ks)*64 + L
//   element = M[ks*32 + (L>>4)*8 + j][ft*16 + (L&15)]
// Also: zeroes y (1 float2/thread), count[], probs_g[].
// ---------------------------------------------------------------------------
__global__ __launch_bounds__(256) void moe_convert(
    const float* __restrict__ w1, const float* __restrict__ w2,
    unsigned short* __restrict__ w1b, unsigned short* __restrict__ w2b,
    int* __restrict__ count, float* __restrict__ probs_g,
    float* __restrict__ y)
{
    __shared__ float ts[32][65];   // 32 k-rows x 64 n-cols (+pad)
    int tid = threadIdx.x;
    {
        size_t gid = (size_t)blockIdx.x * 256 + tid;
        ((float2*)y)[gid] = make_float2(0.f, 0.f);
    }
    if (blockIdx.x == 0 && tid < E_NUM) { count[tid] = 0; probs_g[tid] = 0.f; }

    int b = blockIdx.x;
    bool is2 = b >= 4096;
    int o = is2 ? b - 4096 : b;
    int e = o >> 9, r = o & 511;
    int N  = is2 ? 512 : 2048;
    int Ks = is2 ? 64 : 16;
    int ng, ks;
    if (!is2) { ng = r & 31; ks = r >> 5; }
    else      { ng = r & 7;  ks = r >> 3; }

    const float* src = (is2 ? w2 : w1) + ((size_t)e << 20) + (size_t)(ks * 32) * N + ng * 64;
    int row = tid >> 3, c4 = (tid & 7) * 4;
    f32x4 v0 = *(const f32x4*)(src + (size_t)row * N + c4);
    f32x4 v1 = *(const f32x4*)(src + (size_t)row * N + c4 + 32);
    *(f32x4*)&ts[row][c4] = v0;
    *(f32x4*)&ts[row][c4 + 32] = v1;
    __syncthreads();

    int f = tid >> 6, L = tid & 63, q = L >> 4, n = L & 15;
    float v[8];
#pragma unroll
    for (int j = 0; j < 8; ++j) v[j] = ts[q * 8 + j][f * 16 + n];
    uint4 pk;
    pk.x = pack2(v[0], v[1]); pk.y = pack2(v[2], v[3]);
    pk.z = pack2(v[4], v[5]); pk.w = pack2(v[6], v[7]);
    size_t fraglane = ((size_t)((e * (N / 16) + ng * 4 + f) * Ks + ks)) * 64 + L;
    unsigned short* dst = (is2 ? w2b : w1b) + fraglane * 8;
    *(uint4*)dst = pk;
}

// ---------------------------------------------------------------------------
// Router: 256 threads = 4 waves; one WAVE per token (8 tokens/wave, looped).
// ---------------------------------------------------------------------------
__global__ __launch_bounds__(256) void moe_router(
    const float* __restrict__ x, const float* __restrict__ gw,
    int* __restrict__ count, int* __restrict__ tok_list,
    float* __restrict__ wgt_list, float* __restrict__ probs_g)
{
    __shared__ float pprob[E_NUM];
    __shared__ int   lcnt[E_NUM];
    __shared__ int   gbase[E_NUM];
    __shared__ int   ltok[E_NUM][64];
    __shared__ float lwgt[E_NUM][64];

    int tid = threadIdx.x;
    if (tid < E_NUM) { pprob[tid] = 0.f; lcnt[tid] = 0; }
    __syncthreads();

    int wv = tid >> 6, lane = tid & 63;

    float gr[64];
    {
        const f32x4* gp = (const f32x4*)(gw + lane * 64);
#pragma unroll
        for (int i = 0; i < 16; ++i) *(f32x4*)&gr[i * 4] = gp[i];
    }

    float wps[E_NUM];
#pragma unroll
    for (int e = 0; e < E_NUM; ++e) wps[e] = 0.f;

#pragma unroll 1
    for (int i = 0; i < 8; ++i) {
        int t = blockIdx.x * 32 + wv * 8 + i;
        const float* xp = x + (size_t)t * D_DIM + lane * 8;
        f32x4 x0 = *(const f32x4*)xp;
        f32x4 x1 = *(const f32x4*)(xp + 4);
        float xv[8] = { x0.x, x0.y, x0.z, x0.w, x1.x, x1.y, x1.z, x1.w };
        float acc[E_NUM];
#pragma unroll
        for (int e = 0; e < E_NUM; ++e) acc[e] = 0.f;
#pragma unroll
        for (int j = 0; j < 8; ++j)
#pragma unroll
            for (int e = 0; e < E_NUM; ++e) acc[e] += xv[j] * gr[j * 8 + e];
#pragma unroll
        for (int off = 1; off < 64; off <<= 1)
#pragma unroll
            for (int e = 0; e < E_NUM; ++e) acc[e] += __shfl_xor(acc[e], off);

        float m = acc[0];
#pragma unroll
        for (int e = 1; e < E_NUM; ++e) m = fmaxf(m, acc[e]);
        float p[E_NUM], s = 0.f;
#pragma unroll
        for (int e = 0; e < E_NUM; ++e) { p[e] = __expf(acc[e] - m); s += p[e]; }
        float inv = 1.f / s;
#pragma unroll
        for (int e = 0; e < E_NUM; ++e) { p[e] *= inv; wps[e] += p[e]; }

        int e1 = 0;
#pragma unroll
        for (int e = 1; e < E_NUM; ++e) if (p[e] > p[e1]) e1 = e;
        int e2 = (e1 == 0) ? 1 : 0;
#pragma unroll
        for (int e = 0; e < E_NUM; ++e) if (e != e1 && p[e] > p[e2]) e2 = e;

        if (lane == 0) {
            float invw = 1.f / (p[e1] + p[e2]);
            int s1 = atomicAdd(&lcnt[e1], 1); ltok[e1][s1] = t; lwgt[e1][s1] = p[e1] * invw;
            int s2 = atomicAdd(&lcnt[e2], 1); ltok[e2][s2] = t; lwgt[e2][s2] = p[e2] * invw;
        }
    }
    if (lane == 0) {
#pragma unroll
        for (int e = 0; e < E_NUM; ++e) atomicAdd(&pprob[e], wps[e]);
    }
    __syncthreads();
    if (tid < E_NUM) {
        gbase[tid] = atomicAdd(&count[tid], lcnt[tid]);
        atomicAdd(&probs_g[tid], pprob[tid]);
    }
    __syncthreads();
    int ee = tid >> 5;
    for (int ss = tid & 31; ss < lcnt[ee]; ss += 32) {
        int dst = ee * T_TOKENS + gbase[ee] + ss;
        tok_list[dst] = ltok[ee][ss];
        wgt_list[dst] = lwgt[ee][ss];
    }
}

// ---------------------------------------------------------------------------
// FFN item = (expert, f-half, 32-token tile). 256 threads = 4 waves.
// LDS ~50 KB + VGPR <=170 (__launch_bounds__(256,3)) -> 3 blocks/CU, 12
// desynced waves/CU (m97 occupancy regime). No manual prefetch (R6: forced
// prefetch+bounds -> spills); TLP hides latency.
// Per wave per chunk: phase A = 4 f-tiles (aA[4][2]), phase B = 8 d-tiles
// (aB[8][2], persists). Merged loop: 16 it x (4 w1 + 4 w2 loads, 16 MFMA).
// ---------------------------------------------------------------------------
__global__ __launch_bounds__(256, 3) void moe_ffn(
    const float* __restrict__ x,
    const unsigned short* __restrict__ w1b, const float* __restrict__ b1,
    const unsigned short* __restrict__ w2b, const float* __restrict__ b2,
    const int* __restrict__ count, const int* __restrict__ tok_list,
    const float* __restrict__ wgt_list, float* __restrict__ y,
    const float* __restrict__ probs_g)
{
    int e   = blockIdx.x & 7;
    int ht  = blockIdx.x >> 3;
    int half = (ht >= N_TILES) ? 1 : 0;
    int tile = ht - half * N_TILES;

    if (blockIdx.x == 0 && threadIdx.x == 0) {
        float s = 0.f;
#pragma unroll
        for (int i = 0; i < E_NUM; ++i) {
            float m = probs_g[i] / (float)T_TOKENS;
            s += m * m;
        }
        y[(size_t)T_TOKENS * D_DIM] = (float)E_NUM * s;
    }

    int cnt = count[e];
    if (tile * TILE_T >= cnt) return;

    __shared__ __align__(16) unsigned short Xf[TILE_T * 64 * 8];   // 32 KB, A-frag order
    __shared__ __align__(16) unsigned short hs[TILE_T][264];       // 16.9 KB, padded
    __shared__ int   stok[TILE_T];
    __shared__ float swgt[TILE_T];

    int tid = threadIdx.x;
    if (tid < TILE_T) {
        int s = tile * TILE_T + tid;
        if (s < cnt) { stok[tid] = tok_list[e * T_TOKENS + s]; swgt[tid] = wgt_list[e * T_TOKENS + s]; }
        else         { stok[tid] = 0; swgt[tid] = 0.f; }
    }
    __syncthreads();

    // ---- stage X tile into LDS in A-fragment order -------------------------
    {
        int tl = tid >> 3;                 // token 0..31
        int kb = (tid & 7) * 64;
        const float* xr = x + (size_t)stok[tl] * D_DIM + kb;
        int mt = tl >> 4, nn = tl & 15;
#pragma unroll
        for (int g = 0; g < 8; ++g) {
            f32x4 v0 = *(const f32x4*)(xr + g * 8);
            f32x4 v1 = *(const f32x4*)(xr + g * 8 + 4);
            int ka = kb + g * 8;
            int ks = ka >> 5, qq = (ka >> 3) & 3;
            uint4 pk;
            pk.x = pack2(v0.x, v0.y); pk.y = pack2(v0.z, v0.w);
            pk.z = pack2(v1.x, v1.y); pk.w = pack2(v1.z, v1.w);
            *(uint4*)&Xf[(size_t)((mt * 16 + ks) * 64 + qq * 16 + nn) * 8] = pk;
        }
    }
    __syncthreads();

    int wv = tid >> 6, lane = tid & 63;
    int q = lane >> 4, n = lane & 15;
    const short8* w1p = (const short8*)w1b;
    const short8* w2p = (const short8*)w2b;

    int c0 = half * 4;

    f32x4 aA[4][2];    // [nt][mt] phase-A accumulators (per chunk)
    f32x4 aB[8][2];    // [dt][mt] phase-B accumulators (persist across chunks)
#pragma unroll
    for (int a = 0; a < 8; ++a)
#pragma unroll
        for (int b = 0; b < 2; ++b) aB[a][b] = (f32x4){0.f, 0.f, 0.f, 0.f};

    // ---- prologue: A(c0) ---------------------------------------------------
    {
#pragma unroll
        for (int a = 0; a < 4; ++a)
#pragma unroll
            for (int b = 0; b < 2; ++b) aA[a][b] = (f32x4){0.f, 0.f, 0.f, 0.f};
        size_t w1L = ((size_t)((e * 128 + c0 * 16 + wv * 4) * 16)) * 64 + lane;
#pragma unroll 4
        for (int ks = 0; ks < 16; ++ks) {
            short8 cw[4];
#pragma unroll
            for (int j = 0; j < 4; ++j) cw[j] = w1p[w1L + (size_t)j * 1024 + ks * 64];
#pragma unroll
            for (int mt = 0; mt < 2; ++mt) {
                short8 a = *(const short8*)&Xf[(size_t)((mt * 16 + ks) * 64 + lane) * 8];
#pragma unroll
                for (int j = 0; j < 4; ++j)
                    aA[j][mt] = __builtin_amdgcn_mfma_f32_16x16x32_bf16(a, cw[j], aA[j][mt], 0, 0, 0);
            }
        }
    }

    // ---- main: epilogue(c) then merged A(c+1)+B(c) (or drain B on last) ----
#pragma unroll 1
    for (int cc = 0; cc < 4; ++cc) {
        int c = c0 + cc;
        __syncthreads();   // previous B readers done with hs
        // write hs(c) = gelu(aA + b1)
#pragma unroll
        for (int nt = 0; nt < 4; ++nt) {
            int fg = (c * 16 + wv * 4 + nt) * 16 + n;
            float bb = b1[e * F_DIM + fg];
            int fl = (wv * 4 + nt) * 16 + n;
#pragma unroll
            for (int mt = 0; mt < 2; ++mt)
#pragma unroll
                for (int r = 0; r < 4; ++r) {
                    float h = aA[nt][mt][r] + bb;
                    h = 0.5f * h * (1.f + erff(h * 0.70710678118654752440f));
                    hs[mt * 16 + q * 4 + r][fl] = f2bf(h);
                }
        }
        __syncthreads();   // hs(c) ready

        size_t w2L = ((size_t)((e * 32 + wv * 8) * 64 + c * 8)) * 64 + lane;
        short8 aH[2];

        if (cc < 3) {
            // merged: A(c+1) + B(c)
#pragma unroll
            for (int a = 0; a < 4; ++a)
#pragma unroll
                for (int b = 0; b < 2; ++b) aA[a][b] = (f32x4){0.f, 0.f, 0.f, 0.f};
            size_t w1L = ((size_t)((e * 128 + (c + 1) * 16 + wv * 4) * 16)) * 64 + lane;
#pragma unroll 2
            for (int it = 0; it < 16; ++it) {
                int fs = it >> 1, dh = it & 1;
                // loads
                short8 cw[4], c2[4];
#pragma unroll
                for (int j = 0; j < 4; ++j) {
                    cw[j] = w1p[w1L + (size_t)j * 1024 + it * 64];
                    c2[j] = w2p[w2L + (size_t)(dh * 4 + j) * 4096 + fs * 64];
                }
                if (dh == 0) {
#pragma unroll
                    for (int mt = 0; mt < 2; ++mt)
                        aH[mt] = *(const short8*)&hs[mt * 16 + n][fs * 32 + q * 8];
                }
                // A-MFMAs
#pragma unroll
                for (int mt = 0; mt < 2; ++mt) {
                    short8 a = *(const short8*)&Xf[(size_t)((mt * 16 + it) * 64 + lane) * 8];
#pragma unroll
                    for (int j = 0; j < 4; ++j)
                        aA[j][mt] = __builtin_amdgcn_mfma_f32_16x16x32_bf16(a, cw[j], aA[j][mt], 0, 0, 0);
                }
                // B-MFMAs
#pragma unroll
                for (int j = 0; j < 4; ++j)
#pragma unroll
                    for (int mt = 0; mt < 2; ++mt)
                        aB[dh * 4 + j][mt] = __builtin_amdgcn_mfma_f32_16x16x32_bf16(aH[mt], c2[j], aB[dh * 4 + j][mt], 0, 0, 0);
            }
        } else {
            // drain: B(c3) only
#pragma unroll 2
            for (int it = 0; it < 16; ++it) {
                int fs = it >> 1, dh = it & 1;
                short8 c2[4];
#pragma unroll
                for (int j = 0; j < 4; ++j)
                    c2[j] = w2p[w2L + (size_t)(dh * 4 + j) * 4096 + fs * 64];
                if (dh == 0) {
#pragma unroll
                    for (int mt = 0; mt < 2; ++mt)
                        aH[mt] = *(const short8*)&hs[mt * 16 + n][fs * 32 + q * 8];
                }
#pragma unroll
                for (int j = 0; j < 4; ++j)
#pragma unroll
                    for (int mt = 0; mt < 2; ++mt)
                        aB[dh * 4 + j][mt] = __builtin_amdgcn_mfma_f32_16x16x32_bf16(aH[mt], c2[j], aB[dh * 4 + j][mt], 0, 0, 0);
            }
        }
    }

    // ---- final epilogue: y += wgt * (out + b2 [half 0 only]) ---------------
#pragma unroll
    for (int dt = 0; dt < 8; ++dt) {
        int d = (wv * 8 + dt) * 16 + n;
        float bb = (half == 0) ? b2[e * D_DIM + d] : 0.f;
#pragma unroll
        for (int mt = 0; mt < 2; ++mt)
#pragma unroll
            for (int r = 0; r < 4; ++r) {
                int m = mt * 16 + q * 4 + r;
                float wg = swgt[m];
                if (wg != 0.f)
                    atomicAdd(y + (size_t)stok[m] * D_DIM + d, wg * (aB[dt][mt][r] + bb));
            }
    }
}

// ---------------------------------------------------------------------------
extern "C" void kernel_launch(void* const* d_in, const int* in_sizes, int n_in,
                              void* d_out, int out_size, void* d_ws, size_t ws_size,
                              hipStream_t stream) {
    const float* x  = (const float*)d_in[0];
    const float* gw = (const float*)d_in[1];
    const float* w1 = (const float*)d_in[2];
    const float* b1 = (const float*)d_in[3];
    const float* w2 = (const float*)d_in[4];
    const float* b2 = (const float*)d_in[5];
    float* out = (float*)d_out;

    char* ws = (char*)d_ws;
    int*   count     = (int*)(ws + WS_COUNT);
    float* probs_g   = (float*)(ws + WS_PROBS);
    int*   tok_list  = (int*)(ws + WS_TOK);
    float* wgt_list  = (float*)(ws + WS_WGT);
    unsigned short* w1b = (unsigned short*)(ws + WS_W1B);
    unsigned short* w2b = (unsigned short*)(ws + WS_W2B);

    moe_convert<<<8192, 256, 0, stream>>>(w1, w2, w1b, w2b, count, probs_g, out);
    moe_router<<<T_TOKENS / 32, 256, 0, stream>>>(x, gw, count, tok_list, wgt_list, probs_g);
    moe_ffn<<<E_NUM * 2 * N_TILES, 256, 0, stream>>>(x, w1b, b1, w2b, b2, count, tok_list, wgt_list, out, probs_g);
}

// Round 8
// 310.232 us; speedup vs baseline: 1.5066x; 1.5066x over previous
//
#include <hip/hip_runtime.h>
#include <stdint.h>

#define T_TOKENS 8192
#define D_DIM 512
#define F_DIM 2048
#define E_NUM 8

typedef short short8 __attribute__((ext_vector_type(8)));
typedef float f32x4 __attribute__((ext_vector_type(4)));

// ---------------- bf16 helpers (RNE, finite inputs) -------------------------
__device__ __forceinline__ unsigned short f2bf(float f) {
    union { float f; unsigned int u; } c; c.f = f;
    unsigned int u = c.u;
    unsigned int r = (u + 0x7fffu + ((u >> 16) & 1u)) >> 16;
    return (unsigned short)r;
}
__device__ __forceinline__ unsigned int pack2(float a, float b) {
    return (unsigned int)f2bf(a) | ((unsigned int)f2bf(b) << 16);
}
// fast gelu: 0.5h(1+tanh(0.79788(h+0.044715h^3))) == h*sigmoid(2u); |Δ|<1e-3
__device__ __forceinline__ float gelu_fast(float h) {
    float a = h * fmaf(h * h, -0.0713548162f, -1.5957691216f);  // -2u
    return h / (1.f + __expf(a));
}

// ws layout (bytes). Padded-slot capacity: sum_e ceil128(cnt_e) <= 16384+8*127
#define SLOT_CAP 17408
#define WS_COUNT 0
#define WS_PROBS 512
#define WS_TOK   16384
#define WS_WGT   (WS_TOK + E_NUM * T_TOKENS * 4)
#define WS_W1B   (1ull << 20)
#define WS_W2B   (WS_W1B + 16777216ull)           // w1b: 8*512*2048*2 B
#define WS_XG    (WS_W2B + 16777216ull)           // w2b: 8*2048*512*2 B
#define WS_HG    (WS_XG + (unsigned long long)SLOT_CAP * D_DIM * 2)
// end = WS_HG + SLOT_CAP*F_DIM*2  ~= 118 MB

// prefix offsets over 128-padded per-expert counts
__device__ __forceinline__ void expert_off(const int* __restrict__ count, int e,
                                           int& off_e, int& cnt_e) {
    int off = 0, ce = 0;
#pragma unroll
    for (int i = 0; i < E_NUM; ++i) {
        int c = count[i];
        if (i == e) ce = c;
        if (i < e) off += (c + 127) & ~127;
    }
    off_e = off; cnt_e = ce;
}

// ---------------------------------------------------------------------------
// Convert w1/w2 fp32 -> bf16 in MFMA B-fragment order:
//   frag-lane linear = ((e*(N/16) + ft)*(K/32) + ks)*64 + L   (short8 units)
//   element = M[ks*32 + (L>>4)*8 + j][ft*16 + (L&15)]
// Also zeroes y, count[], probs_g[].
// ---------------------------------------------------------------------------
__global__ __launch_bounds__(256) void moe_convert(
    const float* __restrict__ w1, const float* __restrict__ w2,
    unsigned short* __restrict__ w1b, unsigned short* __restrict__ w2b,
    int* __restrict__ count, float* __restrict__ probs_g,
    float* __restrict__ y)
{
    __shared__ float ts[32][65];
    int tid = threadIdx.x;
    {
        size_t gid = (size_t)blockIdx.x * 256 + tid;
        ((float2*)y)[gid] = make_float2(0.f, 0.f);
    }
    if (blockIdx.x == 0 && tid < E_NUM) { count[tid] = 0; probs_g[tid] = 0.f; }

    int b = blockIdx.x;
    bool is2 = b >= 4096;
    int o = is2 ? b - 4096 : b;
    int e = o >> 9, r = o & 511;
    int N  = is2 ? 512 : 2048;
    int Ks = is2 ? 64 : 16;
    int ng, ks;
    if (!is2) { ng = r & 31; ks = r >> 5; }
    else      { ng = r & 7;  ks = r >> 3; }

    const float* src = (is2 ? w2 : w1) + ((size_t)e << 20) + (size_t)(ks * 32) * N + ng * 64;
    int row = tid >> 3, c4 = (tid & 7) * 4;
    f32x4 v0 = *(const f32x4*)(src + (size_t)row * N + c4);
    f32x4 v1 = *(const f32x4*)(src + (size_t)row * N + c4 + 32);
    *(f32x4*)&ts[row][c4] = v0;
    *(f32x4*)&ts[row][c4 + 32] = v1;
    __syncthreads();

    int f = tid >> 6, L = tid & 63, q = L >> 4, n = L & 15;
    float v[8];
#pragma unroll
    for (int j = 0; j < 8; ++j) v[j] = ts[q * 8 + j][f * 16 + n];
    uint4 pk;
    pk.x = pack2(v[0], v[1]); pk.y = pack2(v[2], v[3]);
    pk.z = pack2(v[4], v[5]); pk.w = pack2(v[6], v[7]);
    size_t fraglane = ((size_t)((e * (N / 16) + ng * 4 + f) * Ks + ks)) * 64 + L;
    unsigned short* dst = (is2 ? w2b : w1b) + fraglane * 8;
    *(uint4*)dst = pk;
}

// ---------------------------------------------------------------------------
// Router (unchanged from R7; correct and cheap)
// ---------------------------------------------------------------------------
__global__ __launch_bounds__(256) void moe_router(
    const float* __restrict__ x, const float* __restrict__ gw,
    int* __restrict__ count, int* __restrict__ tok_list,
    float* __restrict__ wgt_list, float* __restrict__ probs_g)
{
    __shared__ float pprob[E_NUM];
    __shared__ int   lcnt[E_NUM];
    __shared__ int   gbase[E_NUM];
    __shared__ int   ltok[E_NUM][64];
    __shared__ float lwgt[E_NUM][64];

    int tid = threadIdx.x;
    if (tid < E_NUM) { pprob[tid] = 0.f; lcnt[tid] = 0; }
    __syncthreads();

    int wv = tid >> 6, lane = tid & 63;

    float gr[64];
    {
        const f32x4* gp = (const f32x4*)(gw + lane * 64);
#pragma unroll
        for (int i = 0; i < 16; ++i) *(f32x4*)&gr[i * 4] = gp[i];
    }

    float wps[E_NUM];
#pragma unroll
    for (int e = 0; e < E_NUM; ++e) wps[e] = 0.f;

#pragma unroll 1
    for (int i = 0; i < 8; ++i) {
        int t = blockIdx.x * 32 + wv * 8 + i;
        const float* xp = x + (size_t)t * D_DIM + lane * 8;
        f32x4 x0 = *(const f32x4*)xp;
        f32x4 x1 = *(const f32x4*)(xp + 4);
        float xv[8] = { x0.x, x0.y, x0.z, x0.w, x1.x, x1.y, x1.z, x1.w };
        float acc[E_NUM];
#pragma unroll
        for (int e = 0; e < E_NUM; ++e) acc[e] = 0.f;
#pragma unroll
        for (int j = 0; j < 8; ++j)
#pragma unroll
            for (int e = 0; e < E_NUM; ++e) acc[e] += xv[j] * gr[j * 8 + e];
#pragma unroll
        for (int off = 1; off < 64; off <<= 1)
#pragma unroll
            for (int e = 0; e < E_NUM; ++e) acc[e] += __shfl_xor(acc[e], off);

        float m = acc[0];
#pragma unroll
        for (int e = 1; e < E_NUM; ++e) m = fmaxf(m, acc[e]);
        float p[E_NUM], s = 0.f;
#pragma unroll
        for (int e = 0; e < E_NUM; ++e) { p[e] = __expf(acc[e] - m); s += p[e]; }
        float inv = 1.f / s;
#pragma unroll
        for (int e = 0; e < E_NUM; ++e) { p[e] *= inv; wps[e] += p[e]; }

        int e1 = 0;
#pragma unroll
        for (int e = 1; e < E_NUM; ++e) if (p[e] > p[e1]) e1 = e;
        int e2 = (e1 == 0) ? 1 : 0;
#pragma unroll
        for (int e = 0; e < E_NUM; ++e) if (e != e1 && p[e] > p[e2]) e2 = e;

        if (lane == 0) {
            float invw = 1.f / (p[e1] + p[e2]);
            int s1 = atomicAdd(&lcnt[e1], 1); ltok[e1][s1] = t; lwgt[e1][s1] = p[e1] * invw;
            int s2 = atomicAdd(&lcnt[e2], 1); ltok[e2][s2] = t; lwgt[e2][s2] = p[e2] * invw;
        }
    }
    if (lane == 0) {
#pragma unroll
        for (int e = 0; e < E_NUM; ++e) atomicAdd(&pprob[e], wps[e]);
    }
    __syncthreads();
    if (tid < E_NUM) {
        gbase[tid] = atomicAdd(&count[tid], lcnt[tid]);
        atomicAdd(&probs_g[tid], pprob[tid]);
    }
    __syncthreads();
    int ee = tid >> 5;
    for (int ss = tid & 31; ss < lcnt[ee]; ss += 32) {
        int dst = ee * T_TOKENS + gbase[ee] + ss;
        tok_list[dst] = ltok[ee][ss];
        wgt_list[dst] = lwgt[ee][ss];
    }
}

// ---------------------------------------------------------------------------
// Gather: expert-ordered Xg (bf16, A-frag order), zero-padded to 128 slots.
//   Xg short8-linear = (slot16*16 + kb)*64 + lane; lane = (m&15) + 16*((k>>3)&3)
// Block = (expert, 64-slot tile); thread t: slot = t>>2, k-quarter = t&3.
// Block 0 also writes the load-balance loss (router finished earlier).
// ---------------------------------------------------------------------------
__global__ __launch_bounds__(256) void moe_gather(
    const float* __restrict__ x, const int* __restrict__ count,
    const int* __restrict__ tok_list, unsigned short* __restrict__ Xg,
    const float* __restrict__ probs_g, float* __restrict__ y)
{
    if (blockIdx.x == 0 && threadIdx.x == 0) {
        float s = 0.f;
#pragma unroll
        for (int i = 0; i < E_NUM; ++i) {
            float m = probs_g[i] / (float)T_TOKENS;
            s += m * m;
        }
        y[(size_t)T_TOKENS * D_DIM] = (float)E_NUM * s;
    }

    int e = blockIdx.x & 7, tile = blockIdx.x >> 3;
    int off_e, cnt;
    expert_off(count, e, off_e, cnt);
    int padcnt = (cnt + 127) & ~127;
    if (tile * 64 >= padcnt) return;

    int tid = threadIdx.x;
    int tl = tid >> 2;               // slot in tile 0..63
    int kq = tid & 3;                // 128-k quarter
    int slot = tile * 64 + tl;
    bool valid = slot < cnt;
    int tok = valid ? tok_list[e * T_TOKENS + slot] : 0;
    const float* xr = x + (size_t)tok * D_DIM + kq * 128;
    int base16 = ((off_e + tile * 64) >> 4) + (tl >> 4);
    int mlane = tl & 15;

#pragma unroll 4
    for (int g = 0; g < 16; ++g) {
        uint4 pk;
        if (valid) {
            f32x4 v0 = *(const f32x4*)(xr + g * 8);
            f32x4 v1 = *(const f32x4*)(xr + g * 8 + 4);
            pk.x = pack2(v0.x, v0.y); pk.y = pack2(v0.z, v0.w);
            pk.z = pack2(v1.x, v1.y); pk.w = pack2(v1.z, v1.w);
        } else {
            pk.x = 0; pk.y = 0; pk.z = 0; pk.w = 0;
        }
        int kb = kq * 4 + (g >> 2);
        int lane = mlane + 16 * (g & 3);
        *(uint4*)(Xg + ((size_t)(base16 * 16 + kb) * 64 + lane) * 8) = pk;
    }
}

// ---------------------------------------------------------------------------
// GEMM1: Hg = gelu(Xg @ W1 + b1).  M=cnt_e (128-tile), N=2048 (128-tile), K=512.
// 256 thr = 4 waves; wave (wh=wv>>1, nh=wv&1) owns 64x64 -> acc[4][4].
// K-loop: A,B frags DIRECT from global (coalesced, no LDS, no barriers).
// Epilogue: gelu -> per-wave LDS transpose -> Hg in A-frag order.
// ---------------------------------------------------------------------------
__global__ __launch_bounds__(256) void moe_gemm1(
    const unsigned short* __restrict__ Xg, const unsigned short* __restrict__ w1b,
    const float* __restrict__ b1, const int* __restrict__ count,
    unsigned short* __restrict__ Hg)
{
    int e = blockIdx.x & 7;
    int r = blockIdx.x >> 3;
    int mt = r >> 4, nt = r & 15;
    int off_e, cnt;
    expert_off(count, e, off_e, cnt);
    if (mt * 128 >= cnt) return;

    __shared__ unsigned short us[4][64][72];   // per-wave 64x64 transpose, k-inner

    int tid = threadIdx.x;
    int wv = tid >> 6, lane = tid & 63;
    int wh = wv >> 1, nh = wv & 1;
    int q = lane >> 4, n = lane & 15;

    int slot16b = (off_e >> 4) + mt * 8 + wh * 4;
    const short8* Ap = (const short8*)Xg + (size_t)slot16b * 1024 + lane;
    const short8* Bp = (const short8*)w1b + (size_t)(e * 128 + nt * 8 + nh * 4) * 1024 + lane;

    f32x4 acc[4][4];   // [j(n)][i(m)]
#pragma unroll
    for (int j = 0; j < 4; ++j)
#pragma unroll
        for (int i = 0; i < 4; ++i) acc[j][i] = (f32x4){0.f, 0.f, 0.f, 0.f};

#pragma unroll 2
    for (int ks = 0; ks < 16; ++ks) {
        short8 A[4], B[4];
#pragma unroll
        for (int i = 0; i < 4; ++i) A[i] = Ap[(size_t)i * 1024 + ks * 64];
#pragma unroll
        for (int j = 0; j < 4; ++j) B[j] = Bp[(size_t)j * 1024 + ks * 64];
#pragma unroll
        for (int j = 0; j < 4; ++j)
#pragma unroll
            for (int i = 0; i < 4; ++i)
                acc[j][i] = __builtin_amdgcn_mfma_f32_16x16x32_bf16(A[i], B[j], acc[j][i], 0, 0, 0);
    }

    // epilogue: bias + gelu -> us[m][k] (k-inner)
#pragma unroll
    for (int j = 0; j < 4; ++j) {
        float bb = b1[e * F_DIM + (nt * 8 + nh * 4 + j) * 16 + n];
#pragma unroll
        for (int i = 0; i < 4; ++i)
#pragma unroll
            for (int rr = 0; rr < 4; ++rr)
                us[wv][i * 16 + q * 4 + rr][j * 16 + n] = f2bf(gelu_fast(acc[j][i][rr] + bb));
    }
    __syncthreads();

    // coalesced A-frag stores to Hg: kbg = nt*4 + nh*2 + kb
#pragma unroll
    for (int i = 0; i < 4; ++i)
#pragma unroll
        for (int kb = 0; kb < 2; ++kb) {
            short8 v = *(const short8*)&us[wv][i * 16 + n][kb * 32 + q * 8];
            size_t idx = ((size_t)(slot16b + i) * 64 + (nt * 4 + nh * 2 + kb)) * 64 + lane;
            *(short8*)((unsigned short*)Hg + idx * 8) = v;
        }
}

// ---------------------------------------------------------------------------
// GEMM2: y[tok] += wgt * (Hg @ W2 + b2).  M=cnt_e, N=512 (128-tile), K=2048.
// Same wave structure; A-frags direct from Hg (already A-frag order).
// ---------------------------------------------------------------------------
__global__ __launch_bounds__(256) void moe_gemm2(
    const unsigned short* __restrict__ Hg, const unsigned short* __restrict__ w2b,
    const float* __restrict__ b2, const int* __restrict__ count,
    const int* __restrict__ tok_list, const float* __restrict__ wgt_list,
    float* __restrict__ y)
{
    int e = blockIdx.x & 7;
    int r = blockIdx.x >> 3;
    int mt = r >> 2, nt = r & 3;
    int off_e, cnt;
    expert_off(count, e, off_e, cnt);
    if (mt * 128 >= cnt) return;

    __shared__ int   stok[128];
    __shared__ float swgt[128];

    int tid = threadIdx.x;
    if (tid < 128) {
        int s = mt * 128 + tid;
        if (s < cnt) { stok[tid] = tok_list[e * T_TOKENS + s]; swgt[tid] = wgt_list[e * T_TOKENS + s]; }
        else         { stok[tid] = 0; swgt[tid] = 0.f; }
    }
    __syncthreads();

    int wv = tid >> 6, lane = tid & 63;
    int wh = wv >> 1, nh = wv & 1;
    int q = lane >> 4, n = lane & 15;

    int slot16b = (off_e >> 4) + mt * 8 + wh * 4;
    const short8* Ap = (const short8*)Hg + (size_t)slot16b * 4096 + lane;
    const short8* Bp = (const short8*)w2b + (size_t)(e * 32 + nt * 8 + nh * 4) * 4096 + lane;

    f32x4 acc[4][4];
#pragma unroll
    for (int j = 0; j < 4; ++j)
#pragma unroll
        for (int i = 0; i < 4; ++i) acc[j][i] = (f32x4){0.f, 0.f, 0.f, 0.f};

#pragma unroll 2
    for (int kb = 0; kb < 64; ++kb) {
        short8 A[4], B[4];
#pragma unroll
        for (int i = 0; i < 4; ++i) A[i] = Ap[(size_t)i * 4096 + kb * 64];
#pragma unroll
        for (int j = 0; j < 4; ++j) B[j] = Bp[(size_t)j * 4096 + kb * 64];
#pragma unroll
        for (int j = 0; j < 4; ++j)
#pragma unroll
            for (int i = 0; i < 4; ++i)
                acc[j][i] = __builtin_amdgcn_mfma_f32_16x16x32_bf16(A[i], B[j], acc[j][i], 0, 0, 0);
    }

    // epilogue: y += wgt * (acc + b2)
#pragma unroll
    for (int j = 0; j < 4; ++j) {
        int d = (nt * 8 + nh * 4 + j) * 16 + n;
        float bb = b2[e * D_DIM + d];
#pragma unroll
        for (int i = 0; i < 4; ++i)
#pragma unroll
            for (int rr = 0; rr < 4; ++rr) {
                int m = wh * 64 + i * 16 + q * 4 + rr;
                float wg = swgt[m];
                if (wg != 0.f)
                    atomicAdd(y + (size_t)stok[m] * D_DIM + d, wg * (acc[j][i][rr] + bb));
            }
    }
}

// ---------------------------------------------------------------------------
extern "C" void kernel_launch(void* const* d_in, const int* in_sizes, int n_in,
                              void* d_out, int out_size, void* d_ws, size_t ws_size,
                              hipStream_t stream) {
    const float* x  = (const float*)d_in[0];
    const float* gw = (const float*)d_in[1];
    const float* w1 = (const float*)d_in[2];
    const float* b1 = (const float*)d_in[3];
    const float* w2 = (const float*)d_in[4];
    const float* b2 = (const float*)d_in[5];
    float* out = (float*)d_out;

    char* ws = (char*)d_ws;
    int*   count     = (int*)(ws + WS_COUNT);
    float* probs_g   = (float*)(ws + WS_PROBS);
    int*   tok_list  = (int*)(ws + WS_TOK);
    float* wgt_list  = (float*)(ws + WS_WGT);
    unsigned short* w1b = (unsigned short*)(ws + WS_W1B);
    unsigned short* w2b = (unsigned short*)(ws + WS_W2B);
    unsigned short* Xg  = (unsigned short*)(ws + WS_XG);
    unsigned short* Hg  = (unsigned short*)(ws + WS_HG);

    moe_convert<<<8192, 256, 0, stream>>>(w1, w2, w1b, w2b, count, probs_g, out);
    moe_router<<<T_TOKENS / 32, 256, 0, stream>>>(x, gw, count, tok_list, wgt_list, probs_g);
    moe_gather<<<8 * 128, 256, 0, stream>>>(x, count, tok_list, Xg, probs_g, out);
    moe_gemm1<<<8 * 64 * 16, 256, 0, stream>>>(Xg, w1b, b1, count, Hg);
    moe_gemm2<<<8 * 64 * 4, 256, 0, stream>>>(Hg, w2b, b2, count, tok_list, wgt_list, out);
}